// Round 9
// baseline (316.376 us; speedup 1.0000x reference)
//
#include <hip/hip_runtime.h>
#include <math.h>

#define NB 32        // batches
#define NP 512       // N == M == 512
#define RG 16        // row-groups (blocks) per batch
#define RPB 32       // rows per block
#define ITERS 50
#define EPSV   0.05f
#define INVEPS 20.0f

typedef unsigned long long u64;

// ws layout (float2): parts[2][NB][RG][NP], rhob[2][NB][NP], epi[NB][RG].
// No init pass: harness poison 0xAAAAAAAA as float (-3.03e-13) never equals a
// valid tag float (1..51), so tag-gated reads are poison-safe.
#define N_PARTS (2*NB*RG*NP)
#define N_RHOB  (2*NB*NP)

// ---- relaxed agent-scope tagged 8B exchange: tag+value arrive atomically ----
__device__ __forceinline__ void st64(float2* p, float tag, float val) {
  union { float2 f; u64 u; } c; c.f = make_float2(tag, val);
  __hip_atomic_store((u64*)p, c.u, __ATOMIC_RELAXED, __HIP_MEMORY_SCOPE_AGENT);
}
__device__ __forceinline__ float2 ld64(const float2* p) {
  union { u64 u; float2 f; } c;
  c.u = __hip_atomic_load((const u64*)p, __ATOMIC_RELAXED, __HIP_MEMORY_SCOPE_AGENT);
  return c.f;
}

// ---------------- single fused kernel: setup + 50 linear-Sinkhorn iters + ot ----
// ONE batch per 512-thread block, 32 rows each; grid = 512 = 2 blocks/CU.
// Co-resident blocks belong to independent batches (batch = rb>>4), so poll
// stalls of one block are hidden by the other block's compute (independent
// phase). Two-hop tagged exchange: C publish col-partials -> combiner block
// reduces slice [32rg,32rg+32) -> publishes rho -> A: 1 tagged load/thread.
// Deadlock-safe at any occupancy: batches occupy contiguous block ranges.
__global__ __launch_bounds__(NP, 4) void emd_kernel(
    const float* __restrict__ a_mask, const float* __restrict__ pc_a,
    const float* __restrict__ b_mask, const float* __restrict__ pc_b,
    float2* __restrict__ parts, float2* __restrict__ rhob,
    float2* __restrict__ epi, float* __restrict__ out)
{
  const int rb = blockIdx.x;
  const int b  = rb >> 4;            // batch (contiguous 16-block ranges)
  const int rg = rb & 15;            // row-group 0..15
  const int t  = threadIdx.x;
  const int chunk = t & 15;          // 16 threads per row
  const int lrow  = t >> 4;          // local row 0..31
  const int grow  = rg*RPB + lrow;
  const int lane  = t & 63, wid = t >> 6;
  const int r_st  = t & 15;          // combine: stream index
  const int c_l   = t >> 4;          // combine: col within slice (0..31)
  const int gcol  = 32*rg + c_l;     // combine: global col

  __shared__ __align__(16) float rho_l[NP];   // exp(logv)
  __shared__ __align__(16) float bw_l[NP];    // col masses
  __shared__ __align__(16) float u_l[RPB];    // exp(logu)
  __shared__ __align__(16) float sm[NP];      // setup aw / epilogue scratch
  __shared__ float red[16];

  float4 eKreg[8];      // row slice: row=grow, cols 64*cc+4*chunk+e
  float  eKcol[RPB];    // col slice: col=t, rows rg*32+i
  float  aw_r, bw_t, hub = 0.f;

  // ================= setup: masses, huber, expK caches =================
  {
    const float apt = a_mask[b*NP+t] * pc_a[((size_t)b*NP+t)*3+2];
    const float bpt = b_mask[b*NP+t] * pc_b[((size_t)b*NP+t)*3+2];
    float ra = apt, rv = bpt;
    #pragma unroll
    for (int o = 32; o; o >>= 1) { ra += __shfl_xor(ra, o); rv += __shfl_xor(rv, o); }
    if (lane == 0) { red[wid] = ra; red[8+wid] = rv; }
    __syncthreads();
    float asum = 0.f, bsum = 0.f;
    #pragma unroll
    for (int w = 0; w < 8; ++w) { asum += red[w]; bsum += red[8+w]; }
    const float e = asum - bsum, ae = fabsf(e);
    hub = (ae <= 1.f) ? 0.5f*e*e : (ae - 0.5f);
    sm[t]   = (apt > 0.f) ? apt/asum : 0.f;   // aw
    bw_l[t] = (bpt > 0.f) ? bpt/bsum : 0.f;
    __syncthreads();
    aw_r = sm[grow];
    bw_t = bw_l[t];
    const float ax = pc_a[((size_t)b*NP+grow)*3+0];
    const float ay = pc_a[((size_t)b*NP+grow)*3+1];
    const bool  va = aw_r > 0.f;
    #pragma unroll
    for (int cc = 0; cc < 8; ++cc) {
      float r[4];
      #pragma unroll
      for (int e2 = 0; e2 < 4; ++e2) {
        const int col = 64*cc + 4*chunk + e2;
        const float bx = pc_b[((size_t)b*NP+col)*3+0];
        const float by = pc_b[((size_t)b*NP+col)*3+1];
        const bool  vb = bw_l[col] > 0.f;
        const float dx = ax-bx, dy = ay-by;
        const float d  = sqrtf(dx*dx + dy*dy + 1e-12f);
        r[e2] = (va && vb) ? __expf((-INVEPS)*d) : 1.f;   // K=0 for masked pairs
      }
      eKreg[cc] = make_float4(r[0], r[1], r[2], r[3]);
    }
    const float bx0 = pc_b[((size_t)b*NP+t)*3+0];
    const float by0 = pc_b[((size_t)b*NP+t)*3+1];
    const bool  vb0 = bw_t > 0.f;
    #pragma unroll
    for (int i = 0; i < RPB; ++i) {
      const int row = rg*RPB + i;
      const float axi = pc_a[((size_t)b*NP+row)*3+0];  // wave-uniform -> scalar loads
      const float ayi = pc_a[((size_t)b*NP+row)*3+1];
      const bool  vai = sm[row] > 0.f;
      const float dx = axi-bx0, dy = ayi-by0;
      const float d  = sqrtf(dx*dx + dy*dy + 1e-12f);
      eKcol[i] = (vai && vb0) ? __expf((-INVEPS)*d) : 1.f;
    }
    rho_l[t] = 1.f;     // rho(0) = exp(logv=0) = 1
    __syncthreads();
  }

  // ================= main loop =================
  for (int k = 1; k <= ITERS; ++k) {
    const float tagk = (float)k;
    const int par = k & 1;

    // ---- B: u(k) = aw / sum_j ek*rho(k-1)
    {
      const float4* r4p = (const float4*)rho_l;
      float dot = 0.f;
      #pragma unroll
      for (int cc = 0; cc < 8; ++cc) {
        const float4 g4 = r4p[16*cc + chunk];
        const float4 kk = eKreg[cc];
        dot += kk.x*g4.x + kk.y*g4.y + kk.z*g4.z + kk.w*g4.w;
      }
      #pragma unroll
      for (int o = 8; o; o >>= 1) dot += __shfl_xor(dot, o);   // 16-lane row reduce
      if (chunk == 0) u_l[lrow] = aw_r / fmaxf(dot, 1e-38f);
    }
    __syncthreads();   // u_l ready (also: all rho_l reads done)

    // ---- C: publish tagged col partials s(k)
    {
      const float4* u4p = (const float4*)u_l;
      float sc = 0.f;
      #pragma unroll
      for (int i4 = 0; i4 < 8; ++i4) {
        const float4 uu = u4p[i4];
        sc += eKcol[4*i4+0]*uu.x + eKcol[4*i4+1]*uu.y
            + eKcol[4*i4+2]*uu.z + eKcol[4*i4+3]*uu.w;
      }
      st64(parts + (((size_t)par*NB + b)*RG + rg)*NP + t, tagk, sc);
    }

    // ---- M: combine slice [32rg,32rg+32), publish rho(k)
    {
      const float2* slot = parts + (((size_t)par*NB + b)*RG + r_st)*NP + gcol;
      float2 q = ld64(slot);
      long long spins = 0;
      while (q.x != tagk) {
        __builtin_amdgcn_s_sleep(2);
        q = ld64(slot);
        if (++spins > (1LL<<27)) break;   // fail visibly, never hang
      }
      float S = q.y;
      #pragma unroll
      for (int o = 8; o; o >>= 1) S += __shfl_xor(S, o);       // over 16 streams
      if (r_st == 0)
        st64(rhob + ((size_t)par*NB + b)*NP + gcol, tagk,
             bw_l[gcol] / fmaxf(S, 1e-38f));
    }

    // ---- A: poll rho(k), 1 load per thread
    {
      const float2* slot = rhob + ((size_t)par*NB + b)*NP + t;
      float2 rq = ld64(slot);
      long long spins = 0;
      while (rq.x != tagk) {
        __builtin_amdgcn_s_sleep(2);
        rq = ld64(slot);
        if (++spins > (1LL<<27)) break;
      }
      rho_l[t] = rq.y;
    }
    __syncthreads();   // rho_l(k) ready for next B / epilogue
  }

  // ---- epilogue: ot partial = sum d^2 * u_i * ek * rho_j over my row slice
  float acc = 0.f;
  {
    const float ur = u_l[lrow];                  // u(50)
    const float4* r4p = (const float4*)rho_l;    // rho(50)
    #pragma unroll
    for (int cc = 0; cc < 8; ++cc) {
      const float4 g4 = r4p[16*cc + chunk];
      const float4 kk = eKreg[cc];
      const float ek[4] = {kk.x, kk.y, kk.z, kk.w};
      const float vv[4] = {g4.x, g4.y, g4.z, g4.w};
      #pragma unroll
      for (int e2 = 0; e2 < 4; ++e2) {
        const float lk = __logf(fmaxf(ek[e2], 1e-38f));  // d = -EPS*lk; masked: lk=0 -> d2=0
        const float d2 = (EPSV*lk)*(EPSV*lk);
        const float v  = d2 * ur * ek[e2] * vv[e2];
        acc += (ek[e2] > 0.f) ? v : 0.f;
      }
    }
  }
  // block-reduce, publish tagged epi, rg==0 gathers
  sm[t] = acc;
  __syncthreads();
  if (t < 64) {
    float v = 0.f;
    #pragma unroll
    for (int q = 0; q < 8; ++q) v += sm[t*8+q];
    #pragma unroll
    for (int o = 32; o; o >>= 1) v += __shfl_xor(v, o);
    if (t == 0) st64(epi + (size_t)b*RG + rg, 51.f, v);
  }
  if (rg == 0 && t < 16) {     // gather: 16 lanes, poll + shfl-reduce
    float2 pr;
    long long spins = 0;
    do {
      pr = ld64(epi + (size_t)b*RG + t);
      if (pr.x == 51.f) break;
      __builtin_amdgcn_s_sleep(2);
    } while (++spins < (1LL<<27));
    float v = pr.y;
    #pragma unroll
    for (int o = 8; o; o >>= 1) v += __shfl_xor(v, o);
    if (t == 0) out[b] = v + hub;
  }
}

extern "C" void kernel_launch(void* const* d_in, const int* in_sizes, int n_in,
                              void* d_out, int out_size, void* d_ws, size_t ws_size,
                              hipStream_t stream) {
  const float* a_mask = (const float*)d_in[0];
  const float* pc_a   = (const float*)d_in[1];
  const float* b_mask = (const float*)d_in[2];
  const float* pc_b   = (const float*)d_in[3];
  float* out = (float*)d_out;
  float2* parts = (float2*)d_ws;            // 4 MiB
  float2* rhob  = parts + N_PARTS;          // + 256 KiB
  float2* epi   = rhob + N_RHOB;            // + 4 KiB
  (void)in_sizes; (void)n_in; (void)out_size; (void)ws_size;

  emd_kernel<<<NB*RG, NP, 0, stream>>>(a_mask, pc_a, b_mask, pc_b,
                                       parts, rhob, epi, out);
}

// Round 10
// 278.313 us; speedup vs baseline: 1.1368x; 1.1368x over previous
//
#include <hip/hip_runtime.h>
#include <math.h>

#define NB 32        // batches
#define NP 512       // N == M == 512
#define RG 8         // row-groups (blocks) per batch
#define RPB 64       // rows per block
#define ITERS 50
#define EPSV   0.05f
#define INVEPS 20.0f

typedef unsigned long long u64;

// ws layout (float2): parts[2][NB][RG][NP], epi[NB][RG].
// No init pass: harness poison 0xAAAAAAAA as float (-3.03e-13) never equals a
// valid tag float (1..51), so tag-gated reads are poison-safe.
#define N_PARTS (2*NB*RG*NP)

// ---- relaxed agent-scope tagged 8B exchange: tag+value arrive atomically ----
__device__ __forceinline__ void st64(float2* p, float tag, float val) {
  union { float2 f; u64 u; } c; c.f = make_float2(tag, val);
  __hip_atomic_store((u64*)p, c.u, __ATOMIC_RELAXED, __HIP_MEMORY_SCOPE_AGENT);
}
__device__ __forceinline__ float2 ld64(const float2* p) {
  union { u64 u; float2 f; } c;
  c.u = __hip_atomic_load((const u64*)p, __ATOMIC_RELAXED, __HIP_MEMORY_SCOPE_AGENT);
  return c.f;
}

// ---------------- single fused kernel: setup + 50 linear-Sinkhorn iters + ot ----
// ONE batch per 512-thread block, 64 rows each, RG=8 blocks/batch, grid=256.
// SINGLE-HOP exchange: C publishes tagged col-partials; every thread then
// reads its own column's 8 stream entries directly (8 parallel tagged loads),
// sums locally, computes rho. One visibility+discovery per iteration.
// Deadlock-safe: batches occupy contiguous 8-block ranges, always co-resident.
__global__ __launch_bounds__(NP, 2) void emd_kernel(
    const float* __restrict__ a_mask, const float* __restrict__ pc_a,
    const float* __restrict__ b_mask, const float* __restrict__ pc_b,
    float2* __restrict__ parts, float2* __restrict__ epi,
    float* __restrict__ out)
{
  const int rb = blockIdx.x;
  const int b  = rb >> 3;            // batch (contiguous 8-block ranges)
  const int rg = rb & 7;             // row-group 0..7
  const int t  = threadIdx.x;
  const int chunk = t & 7;           // 8 threads per row
  const int lrow  = t >> 3;          // local row 0..63
  const int grow  = rg*RPB + lrow;
  const int lane  = t & 63, wid = t >> 6;

  __shared__ __align__(16) float rho_l[NP];   // exp(logv)
  __shared__ __align__(16) float bw_l[NP];    // col masses
  __shared__ __align__(16) float u_l[RPB];    // exp(logu)
  __shared__ __align__(16) float sm[NP];      // setup aw / epilogue scratch
  __shared__ float red[16];

  float4 eKreg[16];     // row slice: row=grow, cols 32*cc+4*chunk+e
  float  eKcol[RPB];    // col slice: col=t, rows rg*64+i
  float  aw_r, bw_t, hub = 0.f;

  // ================= setup: masses, huber, expK caches =================
  {
    const float apt = a_mask[b*NP+t] * pc_a[((size_t)b*NP+t)*3+2];
    const float bpt = b_mask[b*NP+t] * pc_b[((size_t)b*NP+t)*3+2];
    float ra = apt, rv = bpt;
    #pragma unroll
    for (int o = 32; o; o >>= 1) { ra += __shfl_xor(ra, o); rv += __shfl_xor(rv, o); }
    if (lane == 0) { red[wid] = ra; red[8+wid] = rv; }
    __syncthreads();
    float asum = 0.f, bsum = 0.f;
    #pragma unroll
    for (int w = 0; w < 8; ++w) { asum += red[w]; bsum += red[8+w]; }
    const float e = asum - bsum, ae = fabsf(e);
    hub = (ae <= 1.f) ? 0.5f*e*e : (ae - 0.5f);
    sm[t]   = (apt > 0.f) ? apt/asum : 0.f;   // aw
    bw_l[t] = (bpt > 0.f) ? bpt/bsum : 0.f;
    __syncthreads();
    aw_r = sm[grow];
    bw_t = bw_l[t];
    const float ax = pc_a[((size_t)b*NP+grow)*3+0];
    const float ay = pc_a[((size_t)b*NP+grow)*3+1];
    const bool  va = aw_r > 0.f;
    #pragma unroll
    for (int cc = 0; cc < 16; ++cc) {
      float r[4];
      #pragma unroll
      for (int e2 = 0; e2 < 4; ++e2) {
        const int col = 32*cc + 4*chunk + e2;
        const float bx = pc_b[((size_t)b*NP+col)*3+0];
        const float by = pc_b[((size_t)b*NP+col)*3+1];
        const bool  vb = bw_l[col] > 0.f;
        const float dx = ax-bx, dy = ay-by;
        const float d  = sqrtf(dx*dx + dy*dy + 1e-12f);
        r[e2] = (va && vb) ? __expf((-INVEPS)*d) : 1.f;   // K=0 for masked pairs
      }
      eKreg[cc] = make_float4(r[0], r[1], r[2], r[3]);
    }
    const float bx0 = pc_b[((size_t)b*NP+t)*3+0];
    const float by0 = pc_b[((size_t)b*NP+t)*3+1];
    const bool  vb0 = bw_t > 0.f;
    #pragma unroll
    for (int i = 0; i < RPB; ++i) {
      const int row = rg*RPB + i;
      const float axi = pc_a[((size_t)b*NP+row)*3+0];  // wave-uniform -> scalar loads
      const float ayi = pc_a[((size_t)b*NP+row)*3+1];
      const bool  vai = sm[row] > 0.f;
      const float dx = axi-bx0, dy = ayi-by0;
      const float d  = sqrtf(dx*dx + dy*dy + 1e-12f);
      eKcol[i] = (vai && vb0) ? __expf((-INVEPS)*d) : 1.f;
    }
    rho_l[t] = 1.f;     // rho(0) = exp(logv=0) = 1
    __syncthreads();
  }

  // ================= main loop =================
  for (int k = 1; k <= ITERS; ++k) {
    const float tagk = (float)k;
    const int par = k & 1;

    // ---- B: u(k) = aw / sum_j ek*rho(k-1)
    {
      const float4* r4p = (const float4*)rho_l;
      float dot = 0.f;
      #pragma unroll
      for (int cc = 0; cc < 16; ++cc) {
        const float4 g4 = r4p[8*cc + chunk];
        const float4 kk = eKreg[cc];
        dot += kk.x*g4.x + kk.y*g4.y + kk.z*g4.z + kk.w*g4.w;
      }
      #pragma unroll
      for (int o = 4; o; o >>= 1) dot += __shfl_xor(dot, o);   // 8-lane row reduce
      if (chunk == 0) u_l[lrow] = aw_r / fmaxf(dot, 1e-38f);
    }
    __syncthreads();   // u_l ready (also: all rho_l reads done)

    // ---- C: publish tagged col partial s(k) for col t
    {
      const float4* u4p = (const float4*)u_l;
      float sc = 0.f;
      #pragma unroll
      for (int i4 = 0; i4 < 16; ++i4) {
        const float4 uu = u4p[i4];
        sc += eKcol[4*i4+0]*uu.x + eKcol[4*i4+1]*uu.y
            + eKcol[4*i4+2]*uu.z + eKcol[4*i4+3]*uu.w;
      }
      st64(parts + (((size_t)par*NB + b)*RG + rg)*NP + t, tagk, sc);
    }

    // ---- A (single hop): read all 8 streams for col t, poll stragglers
    {
      const float2* base = parts + ((size_t)par*NB + b)*RG*NP + t;
      float2 q[RG];
      #pragma unroll
      for (int r = 0; r < RG; ++r) q[r] = ld64(base + (size_t)r*NP);  // 8 in flight
      #pragma unroll
      for (int r = 0; r < RG; ++r) {
        long long spins = 0;
        while (q[r].x != tagk) {
          __builtin_amdgcn_s_sleep(1);
          q[r] = ld64(base + (size_t)r*NP);
          if (++spins > (1LL<<27)) break;   // fail visibly, never hang
        }
      }
      float S = 0.f;
      #pragma unroll
      for (int r = 0; r < RG; ++r) S += q[r].y;
      rho_l[t] = bw_t / fmaxf(S, 1e-38f);
    }
    __syncthreads();   // rho_l(k) ready for next B / epilogue
  }

  // ---- epilogue: ot partial = sum d^2 * u_i * ek * rho_j over my row slice
  float acc = 0.f;
  {
    const float ur = u_l[lrow];                  // u(50)
    const float4* r4p = (const float4*)rho_l;    // rho(50)
    #pragma unroll
    for (int cc = 0; cc < 16; ++cc) {
      const float4 g4 = r4p[8*cc + chunk];
      const float4 kk = eKreg[cc];
      const float ek[4] = {kk.x, kk.y, kk.z, kk.w};
      const float vv[4] = {g4.x, g4.y, g4.z, g4.w};
      #pragma unroll
      for (int e2 = 0; e2 < 4; ++e2) {
        const float lk = __logf(fmaxf(ek[e2], 1e-38f));  // d = -EPS*lk; masked: lk=0 -> d2=0
        const float d2 = (EPSV*lk)*(EPSV*lk);
        const float v  = d2 * ur * ek[e2] * vv[e2];
        acc += (ek[e2] > 0.f) ? v : 0.f;
      }
    }
  }
  // block-reduce, publish tagged epi, rg==0 gathers
  sm[t] = acc;
  __syncthreads();
  if (t < 64) {
    float v = 0.f;
    #pragma unroll
    for (int q = 0; q < 8; ++q) v += sm[t*8+q];
    #pragma unroll
    for (int o = 32; o; o >>= 1) v += __shfl_xor(v, o);
    if (t == 0) st64(epi + (size_t)b*RG + rg, 51.f, v);
  }
  if (rg == 0 && t < RG) {     // gather: 8 lanes, poll + shfl-reduce
    float2 pr;
    long long spins = 0;
    do {
      pr = ld64(epi + (size_t)b*RG + t);
      if (pr.x == 51.f) break;
      __builtin_amdgcn_s_sleep(1);
    } while (++spins < (1LL<<27));
    float v = pr.y;
    #pragma unroll
    for (int o = 4; o; o >>= 1) v += __shfl_xor(v, o);
    if (t == 0) out[b] = v + hub;
  }
}

extern "C" void kernel_launch(void* const* d_in, const int* in_sizes, int n_in,
                              void* d_out, int out_size, void* d_ws, size_t ws_size,
                              hipStream_t stream) {
  const float* a_mask = (const float*)d_in[0];
  const float* pc_a   = (const float*)d_in[1];
  const float* b_mask = (const float*)d_in[2];
  const float* pc_b   = (const float*)d_in[3];
  float* out = (float*)d_out;
  float2* parts = (float2*)d_ws;            // 2 MiB
  float2* epi   = parts + N_PARTS;          // + 2 KiB
  (void)in_sizes; (void)n_in; (void)out_size; (void)ws_size;

  emd_kernel<<<NB*RG, NP, 0, stream>>>(a_mask, pc_a, b_mask, pc_b,
                                       parts, epi, out);
}